// Round 1
// baseline (186.125 us; speedup 1.0000x reference)
//
#include <hip/hip_runtime.h>
#include <hip/hip_bf16.h>
#include <stdint.h>

#define N_SAMPLES 4096
#define M_ROWS 16
#define K_DIM 256
#define H_DIM 256
#define N_CATS 64
#define SPB 4                                        // samples per gemm block
#define MAX_PADDED (N_SAMPLES + N_CATS * (SPB - 1))  // 4288
#define NB (MAX_PADDED / SPB)                        // 1072

typedef _Float16 half8 __attribute__((ext_vector_type(8)));
typedef float floatx4 __attribute__((ext_vector_type(4)));

// ---- workspace layout ----
#define WT_BYTES ((size_t)N_CATS * K_DIM * H_DIM * 2)  // 8 MB f16 W^T
#define CNT_OFF  WT_BYTES
#define CUR_OFF  (CNT_OFF + 256)
#define POFF_OFF (CNT_OFF + 512)
#define ORD_OFF  (CNT_OFF + 1024)
#define WS_NEED  (ORD_OFF + (size_t)MAX_PADDED * 4)

// ---------------- prep kernels ----------------
__global__ void prep_init(int* cnt, int* cur, int* ord) {
  int i = blockIdx.x * 256 + threadIdx.x;
  if (i < N_CATS) { cnt[i] = 0; cur[i] = 0; }
  if (i < MAX_PADDED) ord[i] = -1;
}

__global__ void prep_hist(const int* __restrict__ cat, int* cnt) {
  int i = blockIdx.x * 256 + threadIdx.x;
  if (i < N_SAMPLES) atomicAdd(&cnt[cat[i]], 1);
}

__global__ void prep_scan(const int* __restrict__ cnt, int* poff) {
  if (threadIdx.x == 0) {
    int run = 0;
    for (int c = 0; c < N_CATS; c++) {
      poff[c] = run;
      run += ((cnt[c] + SPB - 1) / SPB) * SPB;
    }
    poff[N_CATS] = run;
  }
}

__global__ void prep_scatter(const int* __restrict__ cat, const int* __restrict__ poff,
                             int* cur, int* __restrict__ ord) {
  int i = blockIdx.x * 256 + threadIdx.x;
  if (i < N_SAMPLES) {
    int c = cat[i];
    int p = poff[c] + atomicAdd(&cur[c], 1);
    ord[p] = i;
  }
}

// W [cat][k][h] fp32  ->  Wt [cat][h][k] f16   (64x64 LDS tile transpose)
__global__ __launch_bounds__(256)
void wt_transpose(const float* __restrict__ W, _Float16* __restrict__ Wt) {
  __shared__ _Float16 t[64][72];  // +8 pad breaks bank conflicts on transpose read
  const int bid = blockIdx.x;
  const int c  = bid >> 4;
  const int kb = (bid >> 2) & 3;
  const int hb = bid & 3;
  const int tid = threadIdx.x;
  const int r  = tid >> 2;           // 0..63
  const int cg = (tid & 3) * 16;
  const float* src = W + ((size_t)c << 16) + (size_t)(kb * 64 + r) * 256 + hb * 64 + cg;
#pragma unroll
  for (int j = 0; j < 16; j += 4) {
    float4 v = *(const float4*)(src + j);
    t[r][cg + j + 0] = (_Float16)v.x;
    t[r][cg + j + 1] = (_Float16)v.y;
    t[r][cg + j + 2] = (_Float16)v.z;
    t[r][cg + j + 3] = (_Float16)v.w;
  }
  __syncthreads();
  _Float16* dst = Wt + ((size_t)c << 16) + (size_t)(hb * 64 + r) * 256 + kb * 64 + cg;
  half8 o0, o1;
#pragma unroll
  for (int j = 0; j < 8; j++) o0[j] = t[cg + j][r];
#pragma unroll
  for (int j = 0; j < 8; j++) o1[j] = t[cg + 8 + j][r];
  *(half8*)(dst) = o0;
  *(half8*)(dst + 8) = o1;
}

// ---------------- main GEMM ----------------
// block: 256 threads (4 waves). 4 same-category samples = 64 rows x 256 cols.
// wave w owns rows 0..63, cols w*64..w*64+63 -> 4x4 tiles of 16x16, K chunks of 32.
__global__ __launch_bounds__(256, 4)
void gemm_kernel(const float* __restrict__ x, const int* __restrict__ cat_ids,
                 const float* __restrict__ bias, const _Float16* __restrict__ Wt,
                 const int* __restrict__ ord, float* __restrict__ out) {
  __shared__ _Float16 sA[64 * 32];     // [row][k]  4 KB
  __shared__ _Float16 sB[H_DIM * 32];  // [h][k]   16 KB
  __shared__ int s_meta[SPB];

  const int tid = threadIdx.x;
  const int b = blockIdx.x;
  if (tid < SPB) s_meta[tid] = ord[b * SPB + tid];
  __syncthreads();
  const int s0 = s_meta[0];
  if (s0 < 0) return;  // block past the padded region (uniform branch)
  const int cat = cat_ids[s0];

  const int wid  = tid >> 6;
  const int lane = tid & 63;
  const int l15  = lane & 15;
  const int quad = lane >> 4;

  // A-staging assignment: row = tid>>2 (0..63), k-octet = tid&3
  const int arow = tid >> 2;
  const int akq  = tid & 3;
  const int asmp = s_meta[arow >> 4];
  const float* asrc = (asmp >= 0)
      ? (x + ((size_t)asmp * 16 + (arow & 15)) * K_DIM + akq * 8) : nullptr;
  _Float16* adst = &sA[arow * 32 + akq * 8];

  const _Float16* wbase = Wt + ((size_t)cat << 16);

  floatx4 acc[4][4];
#pragma unroll
  for (int i = 0; i < 4; i++)
#pragma unroll
    for (int j = 0; j < 4; j++)
#pragma unroll
      for (int e = 0; e < 4; e++) acc[i][j][e] = 0.0f;

  for (int kt = 0; kt < K_DIM / 32; ++kt) {
    __syncthreads();  // previous iteration's fragment reads complete
    // ---- stage A (fp32 -> f16 via VGPR) ----
    if (asrc) {
      const float4* p = (const float4*)(asrc + kt * 32);
      float4 v0 = p[0], v1 = p[1];
      half8 h;
      h[0] = (_Float16)v0.x; h[1] = (_Float16)v0.y;
      h[2] = (_Float16)v0.z; h[3] = (_Float16)v0.w;
      h[4] = (_Float16)v1.x; h[5] = (_Float16)v1.y;
      h[6] = (_Float16)v1.z; h[7] = (_Float16)v1.w;
      *(half8*)adst = h;
    } else {
      half8 h;
#pragma unroll
      for (int j = 0; j < 8; j++) h[j] = (_Float16)0.0f;
      *(half8*)adst = h;
    }
    // ---- stage B via async global->LDS, 16B per lane ----
    // chunk = 16 h-rows x 32 k; lane l -> h = hbase + (l>>2), k-octet = l&3
    // LDS dest = uniform base + lane*16, matching [h][32] layout exactly.
#pragma unroll
    for (int i = 0; i < 4; i++) {
      const int hbase = (wid * 4 + i) * 16;
      const _Float16* g = wbase + (size_t)(hbase + (lane >> 2)) * K_DIM + kt * 32 + (lane & 3) * 8;
      __builtin_amdgcn_global_load_lds(
          (__attribute__((address_space(1))) void*)g,
          (__attribute__((address_space(3))) void*)&sB[hbase * 32], 16, 0, 0);
    }
    __syncthreads();  // compiler drains vmcnt+lgkmcnt here
    // ---- fragments + MFMA ----
    half8 af[4], bf[4];
#pragma unroll
    for (int mt = 0; mt < 4; mt++)
      af[mt] = *(const half8*)&sA[(mt * 16 + l15) * 32 + quad * 8];
#pragma unroll
    for (int nt = 0; nt < 4; nt++)
      bf[nt] = *(const half8*)&sB[(wid * 64 + nt * 16 + l15) * 32 + quad * 8];
#pragma unroll
    for (int mt = 0; mt < 4; mt++)
#pragma unroll
      for (int nt = 0; nt < 4; nt++)
        acc[mt][nt] = __builtin_amdgcn_mfma_f32_16x16x32_f16(af[mt], bf[nt], acc[mt][nt], 0, 0, 0);
  }

  // ---- epilogue: C/D layout col=lane&15, row=quad*4+reg ----
#pragma unroll
  for (int mt = 0; mt < 4; mt++) {
    int s = s_meta[mt];
    if (s < 0) continue;  // dummy pad rows: never stored
    float* obase = out + (size_t)s * 16 * H_DIM;
#pragma unroll
    for (int nt = 0; nt < 4; nt++) {
      int col = wid * 64 + nt * 16 + l15;
      float bv = bias[cat * H_DIM + col];
#pragma unroll
      for (int r = 0; r < 4; r++) {
        int row = quad * 4 + r;
        obase[(size_t)row * H_DIM + col] = acc[mt][nt][r] + bv;
      }
    }
  }
}

// ---------------- fallback (ws too small): naive fp32 ----------------
__global__ __launch_bounds__(256)
void naive_kernel(const float* __restrict__ x, const int* __restrict__ cat,
                  const float* __restrict__ W, const float* __restrict__ bias,
                  float* __restrict__ out) {
  __shared__ float sx[16 * 256];
  const int n = blockIdx.x;
  const int tid = threadIdx.x;
  const int c = cat[n];
  const float* xs = x + (size_t)n * 16 * 256;
  for (int i = tid; i < 16 * 256; i += 256) sx[i] = xs[i];
  __syncthreads();
  const float* Wc = W + ((size_t)c << 16);
  float accv[16];
  float bv = bias[c * 256 + tid];
#pragma unroll
  for (int m = 0; m < 16; m++) accv[m] = bv;
  for (int k = 0; k < 256; k++) {
    float w = Wc[(size_t)k * 256 + tid];
#pragma unroll
    for (int m = 0; m < 16; m++) accv[m] += sx[m * 256 + k] * w;
  }
#pragma unroll
  for (int m = 0; m < 16; m++) out[((size_t)n * 16 + m) * 256 + tid] = accv[m];
}

// ---------------- launcher ----------------
extern "C" void kernel_launch(void* const* d_in, const int* in_sizes, int n_in,
                              void* d_out, int out_size, void* d_ws, size_t ws_size,
                              hipStream_t stream) {
  const float* x    = (const float*)d_in[0];
  const int*   cat  = (const int*)d_in[1];
  const float* W    = (const float*)d_in[2];
  const float* bias = (const float*)d_in[3];
  float* out = (float*)d_out;

  if (ws_size < WS_NEED) {
    naive_kernel<<<N_SAMPLES, 256, 0, stream>>>(x, cat, W, bias, out);
    return;
  }

  char* ws = (char*)d_ws;
  _Float16* Wt = (_Float16*)ws;
  int* cnt  = (int*)(ws + CNT_OFF);
  int* cur  = (int*)(ws + CUR_OFF);
  int* poff = (int*)(ws + POFF_OFF);
  int* ord  = (int*)(ws + ORD_OFF);

  wt_transpose<<<N_CATS * 16, 256, 0, stream>>>(W, Wt);
  prep_init<<<(MAX_PADDED + 255) / 256, 256, 0, stream>>>(cnt, cur, ord);
  prep_hist<<<(N_SAMPLES + 255) / 256, 256, 0, stream>>>(cat, cnt);
  prep_scan<<<1, 64, 0, stream>>>(cnt, poff);
  prep_scatter<<<(N_SAMPLES + 255) / 256, 256, 0, stream>>>(cat, poff, cur, ord);
  gemm_kernel<<<NB, 256, 0, stream>>>(x, cat, bias, Wt, ord, out);
}

// Round 2
// 176.602 us; speedup vs baseline: 1.0539x; 1.0539x over previous
//
#include <hip/hip_runtime.h>
#include <hip/hip_bf16.h>
#include <stdint.h>

#define N_SAMPLES 4096
#define M_ROWS 16
#define K_DIM 256
#define H_DIM 256
#define N_CATS 64
#define SPB 4                                        // samples per group (64 rows)
#define MAX_PADDED (N_SAMPLES + N_CATS * (SPB - 1))  // 4288
#define NGROUP (MAX_PADDED / SPB)                    // 1072
#define GPX (NGROUP / 8)                             // 134 groups per XCD
#define GEMM_GRID (NGROUP * 2)                       // 2144 (two h-halves)

typedef _Float16 half8 __attribute__((ext_vector_type(8)));
typedef float floatx4 __attribute__((ext_vector_type(4)));

// ---- workspace layout ----
#define WT_BYTES ((size_t)N_CATS * K_DIM * H_DIM * 2)  // 8 MB f16 W^T
#define ORD_OFF  WT_BYTES
#define WS_NEED  (ORD_OFF + (size_t)MAX_PADDED * 4)

// ---------------- fused prep: transpose (blocks 0..1023) + bucketing (block 1024) ----
// W [cat][k][h] fp32 -> Wt [cat][h][k] f16 ; plus hist/scan/scatter in one block.
__global__ __launch_bounds__(256)
void prep_combined(const float* __restrict__ W, _Float16* __restrict__ Wt,
                   const int* __restrict__ cat, int* __restrict__ ord) {
  const int tid = threadIdx.x;
  if (blockIdx.x < 1024) {
    // ---- 64x64 tile transpose fp32->f16 ----
    __shared__ _Float16 t[64][72];  // +8 pad: conflict-free transpose read
    const int bid = blockIdx.x;
    const int c  = bid >> 4;
    const int kb = (bid >> 2) & 3;
    const int hb = bid & 3;
    const int r  = tid >> 2;           // 0..63
    const int cg = (tid & 3) * 16;
    const float* src = W + ((size_t)c << 16) + (size_t)(kb * 64 + r) * 256 + hb * 64 + cg;
#pragma unroll
    for (int j = 0; j < 16; j += 4) {
      float4 v = *(const float4*)(src + j);
      t[r][cg + j + 0] = (_Float16)v.x;
      t[r][cg + j + 1] = (_Float16)v.y;
      t[r][cg + j + 2] = (_Float16)v.z;
      t[r][cg + j + 3] = (_Float16)v.w;
    }
    __syncthreads();
    _Float16* dst = Wt + ((size_t)c << 16) + (size_t)(hb * 64 + r) * 256 + kb * 64 + cg;
    half8 o0, o1;
#pragma unroll
    for (int j = 0; j < 8; j++) o0[j] = t[cg + j][r];
#pragma unroll
    for (int j = 0; j < 8; j++) o1[j] = t[cg + 8 + j][r];
    *(half8*)(dst) = o0;
    *(half8*)(dst + 8) = o1;
  } else {
    // ---- bucketing: hist -> padded exclusive scan -> scatter, all in LDS ----
    __shared__ int hist[N_CATS];
    __shared__ int poffs[N_CATS];
    __shared__ int curs[N_CATS];
    if (tid < N_CATS) hist[tid] = 0;
    for (int i = tid; i < MAX_PADDED; i += 256) ord[i] = -1;
    __syncthreads();
    for (int i = tid; i < N_SAMPLES; i += 256) atomicAdd(&hist[cat[i]], 1);
    __syncthreads();
    if (tid == 0) {
      int run = 0;
      for (int c = 0; c < N_CATS; c++) {
        poffs[c] = run;
        run += ((hist[c] + SPB - 1) / SPB) * SPB;
      }
    }
    if (tid < N_CATS) curs[tid] = 0;
    __syncthreads();
    for (int i = tid; i < N_SAMPLES; i += 256) {
      int c = cat[i];
      int p = poffs[c] + atomicAdd(&curs[c], 1);
      ord[p] = i;
    }
  }
}

// ---------------- main GEMM ----------------
// block: 256 threads (4 waves) = 64 rows (4 samples) x 128 cols (one h-half).
// wave w owns cols w*32..w*32+31 -> 4x2 tiles of 16x16, K chunks of 32.
// XCD swizzle: xcd = blockIdx%8 owns a contiguous 134-group category range;
// the two h-halves of a group run on consecutive slots of the same XCD
// (second x read L2-hits; per-XCD Wt working set ~1MB <= 4MB L2).
__global__ __launch_bounds__(256, 8)
void gemm_kernel(const float* __restrict__ x, const int* __restrict__ cat_ids,
                 const float* __restrict__ bias, const _Float16* __restrict__ Wt,
                 const int* __restrict__ ord, float* __restrict__ out) {
  __shared__ _Float16 sA[64 * 32];      // [row][k]  4 KB
  __shared__ _Float16 sB[128 * 32];     // [h_local][k]  8 KB
  __shared__ int s_meta[SPB];

  const int tid = threadIdx.x;
  const int B = blockIdx.x;
  const int xcd = B & 7;
  const int slot = B >> 3;
  const int h_half = slot & 1;
  const int group = xcd * GPX + (slot >> 1);
  const int h0 = h_half << 7;

  if (tid < SPB) s_meta[tid] = ord[group * SPB + tid];
  __syncthreads();
  const int s0 = s_meta[0];
  if (s0 < 0) return;  // fully-padded tail group (uniform branch)
  const int cat = cat_ids[s0];

  const int wid  = tid >> 6;
  const int lane = tid & 63;
  const int l15  = lane & 15;
  const int quad = lane >> 4;

  // A-staging: row = tid>>2 (0..63), k-octet = tid&3
  const int arow = tid >> 2;
  const int akq  = tid & 3;
  const int asmp = s_meta[arow >> 4];
  const float* asrc = (asmp >= 0)
      ? (x + ((size_t)asmp * 16 + (arow & 15)) * K_DIM + akq * 8) : nullptr;
  _Float16* adst = &sA[arow * 32 + akq * 8];

  const _Float16* wbase = Wt + ((size_t)cat << 16);

  floatx4 acc[4][2];
#pragma unroll
  for (int i = 0; i < 4; i++)
#pragma unroll
    for (int j = 0; j < 2; j++)
#pragma unroll
      for (int e = 0; e < 4; e++) acc[i][j][e] = 0.0f;

  for (int kt = 0; kt < K_DIM / 32; ++kt) {
    __syncthreads();  // previous iteration's fragment reads complete
    // ---- stage A (fp32 -> f16 via VGPR) ----
    if (asrc) {
      const float4* p = (const float4*)(asrc + kt * 32);
      float4 v0 = p[0], v1 = p[1];
      half8 h;
      h[0] = (_Float16)v0.x; h[1] = (_Float16)v0.y;
      h[2] = (_Float16)v0.z; h[3] = (_Float16)v0.w;
      h[4] = (_Float16)v1.x; h[5] = (_Float16)v1.y;
      h[6] = (_Float16)v1.z; h[7] = (_Float16)v1.w;
      *(half8*)adst = h;
    } else {
      half8 h;
#pragma unroll
      for (int j = 0; j < 8; j++) h[j] = (_Float16)0.0f;
      *(half8*)adst = h;
    }
    // ---- stage B (128 h-rows x 32 k) via async global->LDS, 16B/lane ----
    // chunk c = wid*64 + lane + 256*j -> h_local = c>>2, octet = c&3;
    // LDS dest = uniform base + lane*16 matches [h][32] layout exactly.
#pragma unroll
    for (int j = 0; j < 2; j++) {
      const int hloc = wid * 16 + 64 * j;
      const _Float16* g = wbase + (size_t)(h0 + hloc + (lane >> 2)) * K_DIM + kt * 32 + (lane & 3) * 8;
      __builtin_amdgcn_global_load_lds(
          (__attribute__((address_space(1))) void*)g,
          (__attribute__((address_space(3))) void*)&sB[hloc * 32], 16, 0, 0);
    }
    __syncthreads();  // compiler drains vmcnt+lgkmcnt here
    // ---- fragments + MFMA ----
    half8 af[4], bf[2];
#pragma unroll
    for (int mt = 0; mt < 4; mt++)
      af[mt] = *(const half8*)&sA[(mt * 16 + l15) * 32 + quad * 8];
#pragma unroll
    for (int nt = 0; nt < 2; nt++)
      bf[nt] = *(const half8*)&sB[(wid * 32 + nt * 16 + l15) * 32 + quad * 8];
#pragma unroll
    for (int mt = 0; mt < 4; mt++)
#pragma unroll
      for (int nt = 0; nt < 2; nt++)
        acc[mt][nt] = __builtin_amdgcn_mfma_f32_16x16x32_f16(af[mt], bf[nt], acc[mt][nt], 0, 0, 0);
  }

  // ---- epilogue: C/D layout col=lane&15, row=quad*4+reg ----
#pragma unroll
  for (int mt = 0; mt < 4; mt++) {
    int s = s_meta[mt];
    if (s < 0) continue;  // pad rows never stored
    float* obase = out + (size_t)s * 16 * H_DIM;
#pragma unroll
    for (int nt = 0; nt < 2; nt++) {
      int col = h0 + wid * 32 + nt * 16 + l15;
      float bv = bias[cat * H_DIM + col];
#pragma unroll
      for (int r = 0; r < 4; r++) {
        int row = quad * 4 + r;
        obase[(size_t)row * H_DIM + col] = acc[mt][nt][r] + bv;
      }
    }
  }
}

// ---------------- fallback (ws too small): naive fp32 ----------------
__global__ __launch_bounds__(256)
void naive_kernel(const float* __restrict__ x, const int* __restrict__ cat,
                  const float* __restrict__ W, const float* __restrict__ bias,
                  float* __restrict__ out) {
  __shared__ float sx[16 * 256];
  const int n = blockIdx.x;
  const int tid = threadIdx.x;
  const int c = cat[n];
  const float* xs = x + (size_t)n * 16 * 256;
  for (int i = tid; i < 16 * 256; i += 256) sx[i] = xs[i];
  __syncthreads();
  const float* Wc = W + ((size_t)c << 16);
  float accv[16];
  float bv = bias[c * 256 + tid];
#pragma unroll
  for (int m = 0; m < 16; m++) accv[m] = bv;
  for (int k = 0; k < 256; k++) {
    float w = Wc[(size_t)k * 256 + tid];
#pragma unroll
    for (int m = 0; m < 16; m++) accv[m] += sx[m * 256 + k] * w;
  }
#pragma unroll
  for (int m = 0; m < 16; m++) out[((size_t)n * 16 + m) * 256 + tid] = accv[m];
}

// ---------------- launcher ----------------
extern "C" void kernel_launch(void* const* d_in, const int* in_sizes, int n_in,
                              void* d_out, int out_size, void* d_ws, size_t ws_size,
                              hipStream_t stream) {
  const float* x    = (const float*)d_in[0];
  const int*   cat  = (const int*)d_in[1];
  const float* W    = (const float*)d_in[2];
  const float* bias = (const float*)d_in[3];
  float* out = (float*)d_out;

  if (ws_size < WS_NEED) {
    naive_kernel<<<N_SAMPLES, 256, 0, stream>>>(x, cat, W, bias, out);
    return;
  }

  char* ws = (char*)d_ws;
  _Float16* Wt = (_Float16*)ws;
  int* ord = (int*)(ws + ORD_OFF);

  prep_combined<<<1025, 256, 0, stream>>>(W, Wt, cat, ord);
  gemm_kernel<<<GEMM_GRID, 256, 0, stream>>>(x, cat, bias, Wt, ord, out);
}

// Round 3
// 169.511 us; speedup vs baseline: 1.0980x; 1.0418x over previous
//
#include <hip/hip_runtime.h>
#include <hip/hip_bf16.h>
#include <stdint.h>

#define N_SAMPLES 4096
#define M_ROWS 16
#define K_DIM 256
#define H_DIM 256
#define N_CATS 64
#define SPB 4                                        // samples per group (64 rows)
#define MAX_PADDED (N_SAMPLES + N_CATS * (SPB - 1))  // 4288
#define NGROUP (MAX_PADDED / SPB)                    // 1072
#define GPX (NGROUP / 8)                             // 134 groups per XCD
#define GEMM_GRID (NGROUP * 2)                       // 2144 (two h-halves)
#define AROW_STRIDE 264                              // 256 + 8 halfs: bank-phase-optimal

typedef _Float16 half8 __attribute__((ext_vector_type(8)));
typedef float floatx4 __attribute__((ext_vector_type(4)));

// ---- workspace layout ----
#define WT_BYTES ((size_t)N_CATS * K_DIM * H_DIM * 2)  // 8 MB f16 W^T
#define ORD_OFF  WT_BYTES
#define WS_NEED  (ORD_OFF + (size_t)MAX_PADDED * 4)

// ---------------- fused prep: transpose (blocks 0..1023) + bucketing (block 1024) ----
__global__ __launch_bounds__(256)
void prep_combined(const float* __restrict__ W, _Float16* __restrict__ Wt,
                   const int* __restrict__ cat, int* __restrict__ ord) {
  const int tid = threadIdx.x;
  if (blockIdx.x < 1024) {
    __shared__ _Float16 t[64][72];
    const int bid = blockIdx.x;
    const int c  = bid >> 4;
    const int kb = (bid >> 2) & 3;
    const int hb = bid & 3;
    const int r  = tid >> 2;
    const int cg = (tid & 3) * 16;
    const float* src = W + ((size_t)c << 16) + (size_t)(kb * 64 + r) * 256 + hb * 64 + cg;
#pragma unroll
    for (int j = 0; j < 16; j += 4) {
      float4 v = *(const float4*)(src + j);
      t[r][cg + j + 0] = (_Float16)v.x;
      t[r][cg + j + 1] = (_Float16)v.y;
      t[r][cg + j + 2] = (_Float16)v.z;
      t[r][cg + j + 3] = (_Float16)v.w;
    }
    __syncthreads();
    _Float16* dst = Wt + ((size_t)c << 16) + (size_t)(hb * 64 + r) * 256 + kb * 64 + cg;
    half8 o0, o1;
#pragma unroll
    for (int j = 0; j < 8; j++) o0[j] = t[cg + j][r];
#pragma unroll
    for (int j = 0; j < 8; j++) o1[j] = t[cg + 8 + j][r];
    *(half8*)(dst) = o0;
    *(half8*)(dst + 8) = o1;
  } else {
    __shared__ int hist[N_CATS];
    __shared__ int poffs[N_CATS];
    __shared__ int curs[N_CATS];
    if (tid < N_CATS) hist[tid] = 0;
    for (int i = tid; i < MAX_PADDED; i += 256) ord[i] = -1;
    __syncthreads();
    for (int i = tid; i < N_SAMPLES; i += 256) atomicAdd(&hist[cat[i]], 1);
    __syncthreads();
    if (tid == 0) {
      int run = 0;
      for (int c = 0; c < N_CATS; c++) {
        poffs[c] = run;
        run += ((hist[c] + SPB - 1) / SPB) * SPB;
      }
    }
    if (tid < N_CATS) curs[tid] = 0;
    __syncthreads();
    for (int i = tid; i < N_SAMPLES; i += 256) {
      int c = cat[i];
      int p = poffs[c] + atomicAdd(&curs[c], 1);
      ord[p] = i;
    }
  }
}

// ---------------- main GEMM: one-shot staging, single barrier, no K-loop drains ----
// block = 64 rows (4 samples) x 128 cols (one h-half); wave w owns cols w*32..+31
// (4 m-tiles x 2 n-tiles of 16x16, K=256 in 8 MFMA steps).
// A: fp32->f16 staged once into LDS [64][264] (phase-optimal b128 banking).
// B: straight global->VGPR fragments (Wt is L2-hot from XCD pairing), issued
//    before the barrier so latency overlaps A staging. MFMA phase: LDS + MFMA only.
__global__ __launch_bounds__(256, 4)
void gemm_kernel(const float* __restrict__ x, const int* __restrict__ cat_ids,
                 const float* __restrict__ bias, const _Float16* __restrict__ Wt,
                 const int* __restrict__ ord, float* __restrict__ out) {
  __shared__ _Float16 sA[64 * AROW_STRIDE];  // 33 KB
  __shared__ int s_meta[SPB];

  const int tid = threadIdx.x;
  const int B = blockIdx.x;
  const int xcd = B & 7;
  const int slot = B >> 3;
  const int h_half = slot & 1;
  const int group = xcd * GPX + (slot >> 1);
  const int h0 = h_half << 7;

  if (tid < SPB) s_meta[tid] = ord[group * SPB + tid];
  __syncthreads();
  const int s0 = s_meta[0];
  if (s0 < 0) return;  // fully-padded tail group (uniform)
  const int cat = cat_ids[s0];

  const int wid  = tid >> 6;
  const int lane = tid & 63;
  const int l15  = lane & 15;
  const int quad = lane >> 4;

  // ---- A staging: thread t handles row r = t>>2, k-quarter q = t&3 ----
  const int r = tid >> 2;
  const int q = tid & 3;
  const int smp = s_meta[r >> 4];  // wave-uniform
  const float* asrc = (smp >= 0)
      ? (x + ((size_t)smp * 16 + (r & 15)) * K_DIM + q * 64) : nullptr;
  _Float16* adst = &sA[r * AROW_STRIDE];

#pragma unroll
  for (int hf = 0; hf < 2; hf++) {
    float4 v[8];
    if (asrc) {
#pragma unroll
      for (int j = 0; j < 8; j++) v[j] = ((const float4*)asrc)[hf * 8 + j];
    } else {
#pragma unroll
      for (int j = 0; j < 8; j++) v[j] = make_float4(0.f, 0.f, 0.f, 0.f);
    }
#pragma unroll
    for (int oj = 0; oj < 4; oj++) {
      half8 h;
      h[0] = (_Float16)v[oj * 2].x;     h[1] = (_Float16)v[oj * 2].y;
      h[2] = (_Float16)v[oj * 2].z;     h[3] = (_Float16)v[oj * 2].w;
      h[4] = (_Float16)v[oj * 2 + 1].x; h[5] = (_Float16)v[oj * 2 + 1].y;
      h[6] = (_Float16)v[oj * 2 + 1].z; h[7] = (_Float16)v[oj * 2 + 1].w;
      *(half8*)&adst[(q * 8 + hf * 4 + oj) * 8] = h;
    }
  }

  // ---- B fragments: global -> VGPR, all 16 issued before the barrier ----
  const _Float16* wbase = Wt + ((size_t)cat << 16);
  half8 bf[8][2];
#pragma unroll
  for (int kt = 0; kt < 8; kt++)
#pragma unroll
    for (int nt = 0; nt < 2; nt++) {
      const int col = h0 + wid * 32 + nt * 16 + l15;
      bf[kt][nt] = *(const half8*)(wbase + (size_t)col * K_DIM + kt * 32 + quad * 8);
    }

  floatx4 acc[4][2];
#pragma unroll
  for (int i = 0; i < 4; i++)
#pragma unroll
    for (int j = 0; j < 2; j++)
#pragma unroll
      for (int e = 0; e < 4; e++) acc[i][j][e] = 0.0f;

  __syncthreads();  // the ONLY compute barrier

  // ---- MFMA phase: LDS reads + MFMA only; 8 independent acc chains ----
#pragma unroll
  for (int kt = 0; kt < 8; kt++) {
    half8 af[4];
#pragma unroll
    for (int mt = 0; mt < 4; mt++)
      af[mt] = *(const half8*)&sA[(mt * 16 + l15) * AROW_STRIDE + (kt * 4 + quad) * 8];
#pragma unroll
    for (int mt = 0; mt < 4; mt++)
#pragma unroll
      for (int nt = 0; nt < 2; nt++)
        acc[mt][nt] = __builtin_amdgcn_mfma_f32_16x16x32_f16(af[mt], bf[kt][nt], acc[mt][nt], 0, 0, 0);
  }

  // ---- epilogue: C/D layout col=lane&15, row=quad*4+reg ----
  float bv[2];
#pragma unroll
  for (int nt = 0; nt < 2; nt++)
    bv[nt] = bias[cat * H_DIM + h0 + wid * 32 + nt * 16 + l15];
#pragma unroll
  for (int mt = 0; mt < 4; mt++) {
    int s = s_meta[mt];
    if (s < 0) continue;
    float* obase = out + (size_t)s * 16 * H_DIM;
#pragma unroll
    for (int nt = 0; nt < 2; nt++) {
      int col = h0 + wid * 32 + nt * 16 + l15;
#pragma unroll
      for (int rr = 0; rr < 4; rr++) {
        int row = quad * 4 + rr;
        obase[(size_t)row * H_DIM + col] = acc[mt][nt][rr] + bv[nt];
      }
    }
  }
}

// ---------------- fallback (ws too small): naive fp32 ----------------
__global__ __launch_bounds__(256)
void naive_kernel(const float* __restrict__ x, const int* __restrict__ cat,
                  const float* __restrict__ W, const float* __restrict__ bias,
                  float* __restrict__ out) {
  __shared__ float sx[16 * 256];
  const int n = blockIdx.x;
  const int tid = threadIdx.x;
  const int c = cat[n];
  const float* xs = x + (size_t)n * 16 * 256;
  for (int i = tid; i < 16 * 256; i += 256) sx[i] = xs[i];
  __syncthreads();
  const float* Wc = W + ((size_t)c << 16);
  float accv[16];
  float bv = bias[c * 256 + tid];
#pragma unroll
  for (int m = 0; m < 16; m++) accv[m] = bv;
  for (int k = 0; k < 256; k++) {
    float w = Wc[(size_t)k * 256 + tid];
#pragma unroll
    for (int m = 0; m < 16; m++) accv[m] += sx[m * 256 + k] * w;
  }
#pragma unroll
  for (int m = 0; m < 16; m++) out[((size_t)n * 16 + m) * 256 + tid] = accv[m];
}

// ---------------- launcher ----------------
extern "C" void kernel_launch(void* const* d_in, const int* in_sizes, int n_in,
                              void* d_out, int out_size, void* d_ws, size_t ws_size,
                              hipStream_t stream) {
  const float* x    = (const float*)d_in[0];
  const int*   cat  = (const int*)d_in[1];
  const float* W    = (const float*)d_in[2];
  const float* bias = (const float*)d_in[3];
  float* out = (float*)d_out;

  if (ws_size < WS_NEED) {
    naive_kernel<<<N_SAMPLES, 256, 0, stream>>>(x, cat, W, bias, out);
    return;
  }

  char* ws = (char*)d_ws;
  _Float16* Wt = (_Float16*)ws;
  int* ord = (int*)(ws + ORD_OFF);

  prep_combined<<<1025, 256, 0, stream>>>(W, Wt, cat, ord);
  gemm_kernel<<<GEMM_GRID, 256, 0, stream>>>(x, cat, bias, Wt, ord, out);
}

// Round 4
// 161.198 us; speedup vs baseline: 1.1546x; 1.0516x over previous
//
#include <hip/hip_runtime.h>
#include <hip/hip_bf16.h>
#include <stdint.h>

#define N_SAMPLES 4096
#define M_ROWS 16
#define K_DIM 256
#define H_DIM 256
#define N_CATS 64
#define SPB 4                                        // samples per group (64 rows)
#define MAX_PADDED (N_SAMPLES + N_CATS * (SPB - 1))  // 4288
#define NGROUP (MAX_PADDED / SPB)                    // 1072
#define GPX (NGROUP / 8)                             // 134 groups per XCD
#define GEMM_GRID (NGROUP * 2)                       // 2144 (two h-halves)
#define AROW 264                                     // 256+8 halfs; 528B row: 16B-aligned, stride!=0 mod 128B

typedef _Float16 half8 __attribute__((ext_vector_type(8)));
typedef _Float16 half4 __attribute__((ext_vector_type(4)));
typedef float floatx4 __attribute__((ext_vector_type(4)));

// ---- workspace layout ----
#define WT_BYTES ((size_t)N_CATS * K_DIM * H_DIM * 2)  // 8 MB f16 W^T
#define GCAT_OFF WT_BYTES                              // NGROUP ints (4288 B, 16B-mult)
#define ORD_OFF  (WT_BYTES + 4288)
#define WS_NEED  (ORD_OFF + (size_t)MAX_PADDED * 4)

// ---------------- fused prep: transpose (blocks 0..1023) + bucketing (block 1024) ----
__global__ __launch_bounds__(256)
void prep_combined(const float* __restrict__ W, _Float16* __restrict__ Wt,
                   const int* __restrict__ cat, int* __restrict__ ord,
                   int* __restrict__ gcat) {
  const int tid = threadIdx.x;
  if (blockIdx.x < 1024) {
    __shared__ _Float16 t[64][72];
    const int bid = blockIdx.x;
    const int c  = bid >> 4;
    const int kb = (bid >> 2) & 3;
    const int hb = bid & 3;
    const int r  = tid >> 2;
    const int cg = (tid & 3) * 16;
    const float* src = W + ((size_t)c << 16) + (size_t)(kb * 64 + r) * 256 + hb * 64 + cg;
#pragma unroll
    for (int j = 0; j < 16; j += 4) {
      float4 v = *(const float4*)(src + j);
      t[r][cg + j + 0] = (_Float16)v.x;
      t[r][cg + j + 1] = (_Float16)v.y;
      t[r][cg + j + 2] = (_Float16)v.z;
      t[r][cg + j + 3] = (_Float16)v.w;
    }
    __syncthreads();
    _Float16* dst = Wt + ((size_t)c << 16) + (size_t)(hb * 64 + r) * 256 + kb * 64 + cg;
    half8 o0, o1;
#pragma unroll
    for (int j = 0; j < 8; j++) o0[j] = t[cg + j][r];
#pragma unroll
    for (int j = 0; j < 8; j++) o1[j] = t[cg + 8 + j][r];
    *(half8*)(dst) = o0;
    *(half8*)(dst + 8) = o1;
  } else {
    __shared__ int hist[N_CATS];
    __shared__ int poffs[N_CATS];
    __shared__ int curs[N_CATS];
    if (tid < N_CATS) hist[tid] = 0;
    for (int i = tid; i < MAX_PADDED; i += 256) ord[i] = -1;
    for (int i = tid; i < NGROUP; i += 256) gcat[i] = 0;
    __syncthreads();
    for (int i = tid; i < N_SAMPLES; i += 256) atomicAdd(&hist[cat[i]], 1);
    __syncthreads();
    if (tid == 0) {
      int run = 0;
      for (int c = 0; c < N_CATS; c++) {
        poffs[c] = run;
        run += ((hist[c] + SPB - 1) / SPB) * SPB;
      }
    }
    if (tid < N_CATS) curs[tid] = 0;
    __syncthreads();
    if (tid < N_CATS) {
      const int c = tid;
      const int g0 = poffs[c] >> 2;
      const int ng = (hist[c] + SPB - 1) >> 2;
      for (int g = 0; g < ng; g++) gcat[g0 + g] = c;
    }
    for (int i = tid; i < N_SAMPLES; i += 256) {
      int c = cat[i];
      int p = poffs[c] + atomicAdd(&curs[c], 1);
      ord[p] = i;
    }
  }
}

// ---------------- main GEMM ----------------
// block = 64 rows (4 samples) x 128 cols (one h-half); wave w owns cols w*32..+31.
// A: wave w stages its own sample COALESCED (1KB/instr, 16 lines) fp32->f16 into
//    padded LDS [64][264] with conflict-free b64 writes. One barrier total.
// B: line-optimal frag-direct loads (16x64B lines/instr); kt 0..3 pre-barrier
//    (pinned by sched_barrier), kt 4..7 rolling-prefetched inside the unrolled
//    MFMA loop -> L2 latency covered by ~3 MFMA groups + TLP.
__global__ __launch_bounds__(256, 4)
void gemm_kernel(const float* __restrict__ x, const float* __restrict__ bias,
                 const _Float16* __restrict__ Wt, const int* __restrict__ ord,
                 const int* __restrict__ gcat, float* __restrict__ out) {
  __shared__ __align__(16) _Float16 sA[64 * AROW];  // 33 KB

  const int tid = threadIdx.x;
  const int B = blockIdx.x;
  const int xcd = B & 7;
  const int slot = B >> 3;
  const int h_half = slot & 1;
  const int group = xcd * GPX + (slot >> 1);
  const int h0 = h_half << 7;

  const int cat = gcat[group];                 // independent of ord (gcat pre-zeroed)
  const int4 sm = *(const int4*)(ord + group * 4);
  if (sm.x < 0) return;                        // fully-padded tail group (uniform)

  const int wid  = tid >> 6;
  const int lane = tid & 63;
  const int l15  = lane & 15;
  const int quad = lane >> 4;

  const _Float16* wbase = Wt + ((size_t)cat << 16);

  // ---- B fragments kt=0..3: issue FIRST (latency headroom) ----
  half8 bf[8][2];
#pragma unroll
  for (int kt = 0; kt < 4; kt++)
#pragma unroll
    for (int nt = 0; nt < 2; nt++) {
      const int col = h0 + wid * 32 + nt * 16 + l15;
      bf[kt][nt] = *(const half8*)(wbase + (size_t)col * K_DIM + kt * 32 + quad * 8);
    }
  __builtin_amdgcn_sched_barrier(0);  // keep these loads issued before A staging

  // ---- A staging: wave w stages sample sm[w], fully coalesced ----
  const int smp = (wid == 0) ? sm.x : (wid == 1) ? sm.y : (wid == 2) ? sm.z : sm.w;
  const float* asrc = (smp >= 0) ? (x + ((size_t)smp << 12)) : nullptr;
  _Float16* adst = sA + (size_t)(wid * 16) * AROW;
  if (asrc) {
#pragma unroll
    for (int j = 0; j < 16; j++) {
      float4 v = *(const float4*)(asrc + j * 256 + lane * 4);
      half4 h;
      h[0] = (_Float16)v.x; h[1] = (_Float16)v.y;
      h[2] = (_Float16)v.z; h[3] = (_Float16)v.w;
      *(half4*)(adst + (size_t)j * AROW + lane * 4) = h;
    }
  } else {
    half4 h;
#pragma unroll
    for (int e = 0; e < 4; e++) h[e] = (_Float16)0.0f;
#pragma unroll
    for (int j = 0; j < 16; j++)
      *(half4*)(adst + (size_t)j * AROW + lane * 4) = h;
  }

  floatx4 acc[4][2];
#pragma unroll
  for (int i = 0; i < 4; i++)
#pragma unroll
    for (int j = 0; j < 2; j++)
#pragma unroll
      for (int e = 0; e < 4; e++) acc[i][j][e] = 0.0f;

  __syncthreads();  // the ONLY barrier (drains A writes; bf kt0-3 also land here)

  // ---- unrolled MFMA phase with rolling B prefetch ----
#pragma unroll
  for (int kt = 0; kt < 8; kt++) {
    if (kt < 4) {  // prefetch kt+4 (compile-time branch; 4 groups of lookahead)
#pragma unroll
      for (int nt = 0; nt < 2; nt++) {
        const int col = h0 + wid * 32 + nt * 16 + l15;
        bf[kt + 4][nt] = *(const half8*)(wbase + (size_t)col * K_DIM + (kt + 4) * 32 + quad * 8);
      }
    }
    half8 af[4];
#pragma unroll
    for (int mt = 0; mt < 4; mt++)
      af[mt] = *(const half8*)&sA[(size_t)(mt * 16 + l15) * AROW + kt * 32 + quad * 8];
#pragma unroll
    for (int mt = 0; mt < 4; mt++)
#pragma unroll
      for (int nt = 0; nt < 2; nt++)
        acc[mt][nt] = __builtin_amdgcn_mfma_f32_16x16x32_f16(af[mt], bf[kt][nt], acc[mt][nt], 0, 0, 0);
  }

  // ---- epilogue: C/D layout col=lane&15, row=quad*4+reg ----
  float bv[2];
#pragma unroll
  for (int nt = 0; nt < 2; nt++)
    bv[nt] = bias[cat * H_DIM + h0 + wid * 32 + nt * 16 + l15];
  const int srow[4] = {sm.x, sm.y, sm.z, sm.w};
#pragma unroll
  for (int mt = 0; mt < 4; mt++) {
    const int s = srow[mt];
    if (s < 0) continue;
    float* obase = out + ((size_t)s << 12);
#pragma unroll
    for (int nt = 0; nt < 2; nt++) {
      const int col = h0 + wid * 32 + nt * 16 + l15;
#pragma unroll
      for (int rr = 0; rr < 4; rr++) {
        const int row = quad * 4 + rr;
        obase[(size_t)row * H_DIM + col] = acc[mt][nt][rr] + bv[nt];
      }
    }
  }
}

// ---------------- fallback (ws too small): naive fp32 ----------------
__global__ __launch_bounds__(256)
void naive_kernel(const float* __restrict__ x, const int* __restrict__ cat,
                  const float* __restrict__ W, const float* __restrict__ bias,
                  float* __restrict__ out) {
  __shared__ float sx[16 * 256];
  const int n = blockIdx.x;
  const int tid = threadIdx.x;
  const int c = cat[n];
  const float* xs = x + (size_t)n * 16 * 256;
  for (int i = tid; i < 16 * 256; i += 256) sx[i] = xs[i];
  __syncthreads();
  const float* Wc = W + ((size_t)c << 16);
  float accv[16];
  float bv = bias[c * 256 + tid];
#pragma unroll
  for (int m = 0; m < 16; m++) accv[m] = bv;
  for (int k = 0; k < 256; k++) {
    float w = Wc[(size_t)k * 256 + tid];
#pragma unroll
    for (int m = 0; m < 16; m++) accv[m] += sx[m * 256 + k] * w;
  }
#pragma unroll
  for (int m = 0; m < 16; m++) out[((size_t)n * 16 + m) * 256 + tid] = accv[m];
}

// ---------------- launcher ----------------
extern "C" void kernel_launch(void* const* d_in, const int* in_sizes, int n_in,
                              void* d_out, int out_size, void* d_ws, size_t ws_size,
                              hipStream_t stream) {
  const float* x    = (const float*)d_in[0];
  const int*   cat  = (const int*)d_in[1];
  const float* W    = (const float*)d_in[2];
  const float* bias = (const float*)d_in[3];
  float* out = (float*)d_out;

  if (ws_size < WS_NEED) {
    naive_kernel<<<N_SAMPLES, 256, 0, stream>>>(x, cat, W, bias, out);
    return;
  }

  char* ws = (char*)d_ws;
  _Float16* Wt = (_Float16*)ws;
  int* gcat = (int*)(ws + GCAT_OFF);
  int* ord  = (int*)(ws + ORD_OFF);

  prep_combined<<<1025, 256, 0, stream>>>(W, Wt, cat, ord, gcat);
  gemm_kernel<<<GEMM_GRID, 256, 0, stream>>>(x, bias, Wt, ord, gcat, out);
}